// Round 1
// baseline (4825.709 us; speedup 1.0000x reference)
//
#include <hip/hip_runtime.h>
#include <math.h>

#define HID 64
#define EMB 8
#define SDEC 20
#define TSEQ 2048

__device__ __forceinline__ float fexp(float x) {
    return __builtin_amdgcn_exp2f(x * 1.44269504088896f);
}
__device__ __forceinline__ float frcp(float x) {
    return __builtin_amdgcn_rcpf(x);
}
__device__ __forceinline__ float fsigmoid(float x) {
    return frcp(1.0f + fexp(-x));
}
__device__ __forceinline__ float ftanh(float x) {
    // tanh(x) = 1 - 2/(e^(2x)+1)
    return 1.0f - 2.0f * frcp(fexp(2.0f * x) + 1.0f);
}
__device__ __forceinline__ float bcast(float v, int k) {
    return __uint_as_float(__builtin_amdgcn_readlane(__float_as_uint(v), (unsigned)k));
}

extern "C" __global__ __launch_bounds__(256, 1) void gru_encdec_kernel(
    const float* __restrict__ input_seq,
    const float* __restrict__ vel_W, const float* __restrict__ vel_b,
    const float* __restrict__ enc_Wih, const float* __restrict__ enc_Whh,
    const float* __restrict__ enc_bih, const float* __restrict__ enc_bhh,
    const float* __restrict__ dec_Wih, const float* __restrict__ dec_Whh,
    const float* __restrict__ dec_bih, const float* __restrict__ dec_bhh,
    const float* __restrict__ lin_W, const float* __restrict__ lin_b,
    float* __restrict__ out, int B)
{
    const int lane = (int)(threadIdx.x & 63);
    const int b = (int)((blockIdx.x * blockDim.x + threadIdx.x) >> 6);
    if (b >= B) return;
    const float* seq = input_seq + (size_t)b * (TSEQ * 2);

    // ---- positional-encoding-folded embedding base: ebase[k] = vel_b[k] + PE[b][k]
    float ebase[EMB];
    #pragma unroll
    for (int i = 0; i < EMB / 2; ++i) {
        float div = expf((float)(2 * i) * -1.1512925464970229f); // -ln(10000)/8
        float arg = (float)b * div;
        ebase[2 * i]     = vel_b[2 * i]     + sinf(arg);
        ebase[2 * i + 1] = vel_b[2 * i + 1] + cosf(arg);
    }

    // ---- encoder gi collapses to gi_g = A[g]*dx + Bc[g]*dy + C[g]
    float A[3], Bc[3], C[3];
    #pragma unroll
    for (int g = 0; g < 3; ++g) {
        int row = g * HID + lane;
        float a = 0.f, bb = 0.f, c = enc_bih[row];
        #pragma unroll
        for (int k = 0; k < EMB; ++k) {
            float w = enc_Wih[row * EMB + k];
            a  += w * vel_W[2 * k];
            bb += w * vel_W[2 * k + 1];
            c  += w * ebase[k];
        }
        A[g] = a; Bc[g] = bb; C[g] = c;
    }
    float bhr = enc_bhh[lane], bhz = enc_bhh[HID + lane], bhn = enc_bhh[2 * HID + lane];

    // ---- recurrent weights in registers: lane j holds rows j, 64+j, 128+j of W_hh
    float wr[HID], wz[HID], wn[HID];
    #pragma unroll
    for (int k = 0; k < HID; ++k) {
        wr[k] = enc_Whh[(0 * HID + lane) * HID + k];
        wz[k] = enc_Whh[(1 * HID + lane) * HID + k];
        wn[k] = enc_Whh[(2 * HID + lane) * HID + k];
    }

    // ---- encoder scan: 2047 steps
    float h = 0.0f;
    float2 p = *(const float2*)(seq);
    for (int t = 0; t < TSEQ - 1; ++t) {
        float2 pn = *(const float2*)(seq + 2 * (t + 1));
        float dx = pn.x - p.x, dy = pn.y - p.y;
        p = pn;
        float gr = C[0] + A[0] * dx + Bc[0] * dy;
        float gz = C[1] + A[1] * dx + Bc[1] * dy;
        float gn = C[2] + A[2] * dx + Bc[2] * dy;
        float hr = bhr, hz = bhz, hn = bhn;
        #pragma unroll
        for (int k = 0; k < HID; ++k) {
            float hk = bcast(h, k);
            hr += hk * wr[k];
            hz += hk * wz[k];
            hn += hk * wn[k];
        }
        float r = fsigmoid(gr + hr);
        float z = fsigmoid(gz + hz);
        float n = ftanh(gn + r * hn);
        h = n + z * (h - n);
    }

    // ---- decoder weights (reuse register arrays)
    #pragma unroll
    for (int k = 0; k < HID; ++k) {
        wr[k] = dec_Whh[(0 * HID + lane) * HID + k];
        wz[k] = dec_Whh[(1 * HID + lane) * HID + k];
        wn[k] = dec_Whh[(2 * HID + lane) * HID + k];
    }
    #pragma unroll
    for (int g = 0; g < 3; ++g) {
        int row = g * HID + lane;
        float a = 0.f, bb = 0.f, c = dec_bih[row];
        #pragma unroll
        for (int k = 0; k < EMB; ++k) {
            float w = dec_Wih[row * EMB + k];
            a  += w * vel_W[2 * k];
            bb += w * vel_W[2 * k + 1];
            c  += w * vel_b[k];   // decoder embedding has no PE
        }
        A[g] = a; Bc[g] = bb; C[g] = c;
    }
    bhr = dec_bhh[lane]; bhz = dec_bhh[HID + lane]; bhn = dec_bhh[2 * HID + lane];

    float lw0 = lin_W[lane], lw1 = lin_W[HID + lane];
    float lb0 = lin_b[0], lb1 = lin_b[1];

    float2 pl = *(const float2*)(seq + 2 * (TSEQ - 1));
    float2 pm = *(const float2*)(seq + 2 * (TSEQ - 2));
    float px0 = pl.x - pm.x, px1 = pl.y - pm.y;
    float off0 = pl.x, off1 = pl.y;

    // ---- decoder: 20 steps
    for (int s = 0; s < SDEC; ++s) {
        float gr = C[0] + A[0] * px0 + Bc[0] * px1;
        float gz = C[1] + A[1] * px0 + Bc[1] * px1;
        float gn = C[2] + A[2] * px0 + Bc[2] * px1;
        float hr = bhr, hz = bhz, hn = bhn;
        #pragma unroll
        for (int k = 0; k < HID; ++k) {
            float hk = bcast(h, k);
            hr += hk * wr[k];
            hz += hk * wz[k];
            hn += hk * wn[k];
        }
        float r = fsigmoid(gr + hr);
        float z = fsigmoid(gz + hz);
        float n = ftanh(gn + r * hn);
        h = n + z * (h - n);

        // x = h @ lin_W.T + lin_b + prev_x  (butterfly reduce over 64 lanes)
        float s0 = h * lw0, s1 = h * lw1;
        #pragma unroll
        for (int o = 32; o; o >>= 1) {
            s0 += __shfl_xor(s0, o, 64);
            s1 += __shfl_xor(s1, o, 64);
        }
        float x0 = s0 + lb0 + px0;
        float x1 = s1 + lb1 + px1;
        if (lane == 0) out[((size_t)b * SDEC + s) * 2 + 0] = x0 + off0;
        if (lane == 1) out[((size_t)b * SDEC + s) * 2 + 1] = x1 + off1;
        px0 = x0; px1 = x1;
    }
}

extern "C" void kernel_launch(void* const* d_in, const int* in_sizes, int n_in,
                              void* d_out, int out_size, void* d_ws, size_t ws_size,
                              hipStream_t stream) {
    const float* input_seq = (const float*)d_in[0];
    const float* vel_W   = (const float*)d_in[1];
    const float* vel_b   = (const float*)d_in[2];
    const float* enc_Wih = (const float*)d_in[3];
    const float* enc_Whh = (const float*)d_in[4];
    const float* enc_bih = (const float*)d_in[5];
    const float* enc_bhh = (const float*)d_in[6];
    const float* dec_Wih = (const float*)d_in[7];
    const float* dec_Whh = (const float*)d_in[8];
    const float* dec_bih = (const float*)d_in[9];
    const float* dec_bhh = (const float*)d_in[10];
    const float* lin_W   = (const float*)d_in[11];
    const float* lin_b   = (const float*)d_in[12];
    float* out = (float*)d_out;

    int B = in_sizes[0] / (TSEQ * 2);           // 4096
    int threads = 256;                          // 4 waves/block, 1 batch elem per wave
    int blocks = (B * 64 + threads - 1) / threads;
    gru_encdec_kernel<<<blocks, threads, 0, stream>>>(
        input_seq, vel_W, vel_b, enc_Wih, enc_Whh, enc_bih, enc_bhh,
        dec_Wih, dec_Whh, dec_bih, dec_bhh, lin_W, lin_b, out, B);
}

// Round 2
// 802.741 us; speedup vs baseline: 6.0115x; 6.0115x over previous
//
#include <hip/hip_runtime.h>
#include <math.h>

#define HID 64
#define EMB 8
#define SDEC 20
#define TSEQ 2048

typedef short short8 __attribute__((ext_vector_type(8)));
typedef float f32x4 __attribute__((ext_vector_type(4)));

union U16x8 { unsigned u[4]; short8 s; uint4 v; };

__device__ __forceinline__ float fexp2(float x){ return __builtin_amdgcn_exp2f(x); }
__device__ __forceinline__ float frcp(float x){ return __builtin_amdgcn_rcpf(x); }
__device__ __forceinline__ float fsigmoid(float x){ return frcp(1.0f + fexp2(-1.44269504f*x)); }
__device__ __forceinline__ float ftanh(float x){ return 1.0f - 2.0f*frcp(fexp2(2.88539008f*x)+1.0f); }
__device__ __forceinline__ unsigned cvt_pk_bf16(float lo, float hi){
    unsigned r;
    asm("v_cvt_pk_bf16_f32 %0, %1, %2" : "=v"(r) : "v"(lo), "v"(hi));
    return r;
}
__device__ __forceinline__ short8 pack_row8(const float* p){
    U16x8 t;
    #pragma unroll
    for (int i = 0; i < 4; ++i) t.u[i] = cvt_pk_bf16(p[2*i], p[2*i+1]);
    return t.s;
}

extern "C" __global__ __launch_bounds__(256, 1) void gru_mfma_kernel(
    const float* __restrict__ in,
    const float* __restrict__ velW, const float* __restrict__ velb,
    const float* __restrict__ eWih, const float* __restrict__ eWhh,
    const float* __restrict__ ebih, const float* __restrict__ ebhh,
    const float* __restrict__ dWih, const float* __restrict__ dWhh,
    const float* __restrict__ dbih, const float* __restrict__ dbhh,
    const float* __restrict__ linW, const float* __restrict__ linb,
    float* __restrict__ out)
{
    __shared__ __align__(16) unsigned char smem[4096];   // 2 bufs x 16 batch x 128B
    const int tid  = (int)threadIdx.x;
    const int lane = tid & 63;
    const int w    = tid >> 6;       // wave 0..3, owns j in [16w, 16w+16)
    const int c    = lane & 15;      // batch col within group / A-frag row
    const int q    = lane >> 4;      // quarter group
    const int b    = (int)blockIdx.x * 16 + c;
    const float* sc = in + (size_t)b * (TSEQ * 2);

    // ---- encoder embedding base: eb[k] = vel_b[k] + PE[b][k]
    float eb[EMB];
    #pragma unroll
    for (int i = 0; i < 4; ++i) {
        float div = __expf((float)(2*i) * -1.1512925464970229f); // -ln(10000)/8
        float arg = (float)b * div;
        eb[2*i]   = velb[2*i]   + __sinf(arg);
        eb[2*i+1] = velb[2*i+1] + __cosf(arg);
    }

    // ---- folded gi constants (encoder): gi_g[j] = A*dx + B*dy + C
    float AR[4],BR[4],CR[4], AZ[4],BZ[4],CZ[4], AN[4],BN[4],CN[4], BH[4];
    #pragma unroll
    for (int r_ = 0; r_ < 4; ++r_) {
        int j = 16*w + 4*q + r_;
        #pragma unroll
        for (int g = 0; g < 3; ++g) {
            int row = g*HID + j;
            float a = 0.f, bb = 0.f, cc = ebih[row];
            #pragma unroll
            for (int k = 0; k < EMB; ++k) {
                float wv = eWih[row*EMB + k];
                a  += wv * velW[2*k];
                bb += wv * velW[2*k+1];
                cc += wv * eb[k];
            }
            if      (g == 0) { AR[r_]=a; BR[r_]=bb; CR[r_]=cc + ebhh[j]; }
            else if (g == 1) { AZ[r_]=a; BZ[r_]=bb; CZ[r_]=cc + ebhh[HID+j]; }
            else             { AN[r_]=a; BN[r_]=bb; CN[r_]=cc; BH[r_]=ebhh[2*HID+j]; }
        }
    }

    // ---- A-fragments: Whh tile (g*4+w), row = 16*tile + c, k = 8q + 32kk + i
    short8 AF[3][2];
    #pragma unroll
    for (int g = 0; g < 3; ++g) {
        int row = 16*(g*4 + w) + c;
        #pragma unroll
        for (int kk = 0; kk < 2; ++kk)
            AF[g][kk] = pack_row8(eWhh + row*HID + 32*kk + 8*q);
    }

    // ---- LDS addresses (XOR-swizzled within each 128B batch-row)
    const int swz    = (c & 7) << 4;
    const int waddr  = c*128 + ((32*w + 8*q) ^ swz);   // this lane's 4 h (8B)
    const int raddr0 = c*128 + (( 16*q      ) ^ swz);  // B-frag kk=0 (16B)
    const int raddr1 = c*128 + (( 16*q + 64 ) ^ swz);  // B-frag kk=1
    const int xaddr0 = c*128 + (( 32*q      ) ^ swz);  // x-proj reads (decoder)
    const int xaddr1 = c*128 + (( 32*q + 16 ) ^ swz);

    // zero-init buffer 0 (h0 = 0)
    *(uint2*)(smem + waddr) = make_uint2(0u, 0u);
    __syncthreads();

    float h0=0.f, h1=0.f, h2=0.f, h3=0.f;
    float2 p0 = *(const float2*)(sc);
    float2 p1 = *(const float2*)(sc + 2);
    float dx = 0.f, dy = 0.f;
    int cur = 0;

    // ================= encoder: 2047 steps =================
    for (int t = 0; t < TSEQ - 1; ++t) {
        int tn = t + 2; tn = tn > TSEQ-1 ? TSEQ-1 : tn;
        float2 pn = *(const float2*)(sc + 2*tn);        // prefetch (used next iter)

        U16x8 bf0, bf1;
        bf0.v = *(const uint4*)(smem + cur*2048 + raddr0);
        bf1.v = *(const uint4*)(smem + cur*2048 + raddr1);

        dx = p1.x - p0.x; dy = p1.y - p0.y;
        f32x4 aR, aZ, aN;
        float giN[4];
        #pragma unroll
        for (int r_ = 0; r_ < 4; ++r_) {
            aR[r_]  = CR[r_] + AR[r_]*dx + BR[r_]*dy;
            aZ[r_]  = CZ[r_] + AZ[r_]*dx + BZ[r_]*dy;
            aN[r_]  = BH[r_];
            giN[r_] = CN[r_] + AN[r_]*dx + BN[r_]*dy;
        }
        aR = __builtin_amdgcn_mfma_f32_16x16x32_bf16(AF[0][0], bf0.s, aR, 0,0,0);
        aR = __builtin_amdgcn_mfma_f32_16x16x32_bf16(AF[0][1], bf1.s, aR, 0,0,0);
        aZ = __builtin_amdgcn_mfma_f32_16x16x32_bf16(AF[1][0], bf0.s, aZ, 0,0,0);
        aZ = __builtin_amdgcn_mfma_f32_16x16x32_bf16(AF[1][1], bf1.s, aZ, 0,0,0);
        aN = __builtin_amdgcn_mfma_f32_16x16x32_bf16(AF[2][0], bf0.s, aN, 0,0,0);
        aN = __builtin_amdgcn_mfma_f32_16x16x32_bf16(AF[2][1], bf1.s, aN, 0,0,0);

        float hh[4] = {h0, h1, h2, h3};
        #pragma unroll
        for (int r_ = 0; r_ < 4; ++r_) {
            float rr = fsigmoid(aR[r_]);
            float zz = fsigmoid(aZ[r_]);
            float nn = ftanh(giN[r_] + rr*aN[r_]);
            hh[r_] = nn + zz*(hh[r_] - nn);
        }
        h0=hh[0]; h1=hh[1]; h2=hh[2]; h3=hh[3];

        unsigned d0 = cvt_pk_bf16(h0, h1);
        unsigned d1 = cvt_pk_bf16(h2, h3);
        *(uint2*)(smem + (cur^1)*2048 + waddr) = make_uint2(d0, d1);

        p0 = p1; p1 = pn;
        __syncthreads();
        cur ^= 1;
    }

    // ================= decoder setup =================
    float px0 = dx, px1 = dy;          // diffs[:, -1]
    float off0 = p0.x, off1 = p0.y;    // input_seq[:, -1, :2]

    #pragma unroll
    for (int r_ = 0; r_ < 4; ++r_) {
        int j = 16*w + 4*q + r_;
        #pragma unroll
        for (int g = 0; g < 3; ++g) {
            int row = g*HID + j;
            float a = 0.f, bb = 0.f, cc = dbih[row];
            #pragma unroll
            for (int k = 0; k < EMB; ++k) {
                float wv = dWih[row*EMB + k];
                a  += wv * velW[2*k];
                bb += wv * velW[2*k+1];
                cc += wv * velb[k];     // no PE in decoder
            }
            if      (g == 0) { AR[r_]=a; BR[r_]=bb; CR[r_]=cc + dbhh[j]; }
            else if (g == 1) { AZ[r_]=a; BZ[r_]=bb; CZ[r_]=cc + dbhh[HID+j]; }
            else             { AN[r_]=a; BN[r_]=bb; CN[r_]=cc; BH[r_]=dbhh[2*HID+j]; }
        }
    }
    #pragma unroll
    for (int g = 0; g < 3; ++g) {
        int row = 16*(g*4 + w) + c;
        #pragma unroll
        for (int kk = 0; kk < 2; ++kk)
            AF[g][kk] = pack_row8(dWhh + row*HID + 32*kk + 8*q);
    }
    float lw0[16], lw1[16];
    #pragma unroll
    for (int u = 0; u < 16; ++u) {
        lw0[u] = linW[16*q + u];
        lw1[u] = linW[HID + 16*q + u];
    }
    float lb0 = linb[0], lb1 = linb[1];
    float* outp = out + (size_t)b * SDEC * 2;

    // ================= decoder: 20 steps =================
    for (int s = 0; s < SDEC; ++s) {
        U16x8 bf0, bf1;
        bf0.v = *(const uint4*)(smem + cur*2048 + raddr0);
        bf1.v = *(const uint4*)(smem + cur*2048 + raddr1);

        f32x4 aR, aZ, aN;
        float giN[4];
        #pragma unroll
        for (int r_ = 0; r_ < 4; ++r_) {
            aR[r_]  = CR[r_] + AR[r_]*px0 + BR[r_]*px1;
            aZ[r_]  = CZ[r_] + AZ[r_]*px0 + BZ[r_]*px1;
            aN[r_]  = BH[r_];
            giN[r_] = CN[r_] + AN[r_]*px0 + BN[r_]*px1;
        }
        aR = __builtin_amdgcn_mfma_f32_16x16x32_bf16(AF[0][0], bf0.s, aR, 0,0,0);
        aR = __builtin_amdgcn_mfma_f32_16x16x32_bf16(AF[0][1], bf1.s, aR, 0,0,0);
        aZ = __builtin_amdgcn_mfma_f32_16x16x32_bf16(AF[1][0], bf0.s, aZ, 0,0,0);
        aZ = __builtin_amdgcn_mfma_f32_16x16x32_bf16(AF[1][1], bf1.s, aZ, 0,0,0);
        aN = __builtin_amdgcn_mfma_f32_16x16x32_bf16(AF[2][0], bf0.s, aN, 0,0,0);
        aN = __builtin_amdgcn_mfma_f32_16x16x32_bf16(AF[2][1], bf1.s, aN, 0,0,0);

        float hh[4] = {h0, h1, h2, h3};
        #pragma unroll
        for (int r_ = 0; r_ < 4; ++r_) {
            float rr = fsigmoid(aR[r_]);
            float zz = fsigmoid(aZ[r_]);
            float nn = ftanh(giN[r_] + rr*aN[r_]);
            hh[r_] = nn + zz*(hh[r_] - nn);
        }
        h0=hh[0]; h1=hh[1]; h2=hh[2]; h3=hh[3];

        unsigned d0 = cvt_pk_bf16(h0, h1);
        unsigned d1 = cvt_pk_bf16(h2, h3);
        *(uint2*)(smem + (cur^1)*2048 + waddr) = make_uint2(d0, d1);
        __syncthreads();

        // x = h_new @ lin_W.T + lin_b + prev_x  (read h_new from LDS, reduce over q)
        U16x8 xu0, xu1;
        xu0.v = *(const uint4*)(smem + (cur^1)*2048 + xaddr0);
        xu1.v = *(const uint4*)(smem + (cur^1)*2048 + xaddr1);
        float s0 = 0.f, s1 = 0.f;
        #pragma unroll
        for (int i = 0; i < 8; ++i) {
            unsigned dw = (i < 4) ? xu0.u[i] : xu1.u[i-4];
            float hlo = __uint_as_float(dw << 16);
            float hhi = __uint_as_float(dw & 0xffff0000u);
            s0 = fmaf(hlo, lw0[2*i], fmaf(hhi, lw0[2*i+1], s0));
            s1 = fmaf(hlo, lw1[2*i], fmaf(hhi, lw1[2*i+1], s1));
        }
        s0 += __shfl_xor(s0, 16); s0 += __shfl_xor(s0, 32);
        s1 += __shfl_xor(s1, 16); s1 += __shfl_xor(s1, 32);
        float x0 = s0 + lb0 + px0;
        float x1 = s1 + lb1 + px1;
        if (tid < 16) *(float2*)(outp + 2*s) = make_float2(x0 + off0, x1 + off1);
        px0 = x0; px1 = x1;
        cur ^= 1;
    }
}

extern "C" void kernel_launch(void* const* d_in, const int* in_sizes, int n_in,
                              void* d_out, int out_size, void* d_ws, size_t ws_size,
                              hipStream_t stream) {
    const float* input_seq = (const float*)d_in[0];
    const float* vel_W   = (const float*)d_in[1];
    const float* vel_b   = (const float*)d_in[2];
    const float* enc_Wih = (const float*)d_in[3];
    const float* enc_Whh = (const float*)d_in[4];
    const float* enc_bih = (const float*)d_in[5];
    const float* enc_bhh = (const float*)d_in[6];
    const float* dec_Wih = (const float*)d_in[7];
    const float* dec_Whh = (const float*)d_in[8];
    const float* dec_bih = (const float*)d_in[9];
    const float* dec_bhh = (const float*)d_in[10];
    const float* lin_W   = (const float*)d_in[11];
    const float* lin_b   = (const float*)d_in[12];
    float* out = (float*)d_out;

    int B = in_sizes[0] / (TSEQ * 2);     // 4096
    int blocks = B / 16;                  // 256 workgroups, 1 per CU
    gru_mfma_kernel<<<blocks, 256, 0, stream>>>(
        input_seq, vel_W, vel_b, enc_Wih, enc_Whh, enc_bih, enc_bhh,
        dec_Wih, dec_Whh, dec_bih, dec_bhh, lin_W, lin_b, out);
}

// Round 4
// 689.365 us; speedup vs baseline: 7.0002x; 1.1645x over previous
//
#include <hip/hip_runtime.h>
#include <math.h>

#define HID 64
#define EMB 8
#define SDEC 20
#define TSEQ 2048

typedef short short8 __attribute__((ext_vector_type(8)));
typedef float f32x4 __attribute__((ext_vector_type(4)));
union U16x8 { unsigned u[4]; short8 s; uint4 v; };

#define SSIG (-1.44269504088896f)   /* -log2(e): sigmoid(x)=rcp(1+exp2(SSIG*x)) */
#define STAN ( 2.88539008177793f)   /* 2*log2(e): tanh(v)=1-2*rcp(1+exp2(STAN*v)) */

__device__ __forceinline__ float fexp2(float x){ return __builtin_amdgcn_exp2f(x); }
__device__ __forceinline__ float frcp(float x){ return __builtin_amdgcn_rcpf(x); }
__device__ __forceinline__ unsigned cvt_pk_bf16(float lo, float hi){
    unsigned r; asm("v_cvt_pk_bf16_f32 %0, %1, %2" : "=v"(r) : "v"(lo), "v"(hi)); return r;
}
__device__ __forceinline__ short8 pack_row8(const float* p, float s){
    U16x8 t;
    #pragma unroll
    for (int i = 0; i < 4; ++i) t.u[i] = cvt_pk_bf16(s*p[2*i], s*p[2*i+1]);
    return t.s;
}
// producer->consumer LDS handoff: wait own ds ops retired, rendezvous, no vmcnt drain
__device__ __forceinline__ void group_barrier(){
    asm volatile("s_waitcnt lgkmcnt(0)" ::: "memory");
    __builtin_amdgcn_s_barrier();
    asm volatile("" ::: "memory");
}

extern "C" __global__ __launch_bounds__(256, 1) void gru_mfma_kernel(
    const float* __restrict__ in,
    const float* __restrict__ velW, const float* __restrict__ velb,
    const float* __restrict__ eWih, const float* __restrict__ eWhh,
    const float* __restrict__ ebih, const float* __restrict__ ebhh,
    const float* __restrict__ dWih, const float* __restrict__ dWhh,
    const float* __restrict__ dbih, const float* __restrict__ dbhh,
    const float* __restrict__ linW, const float* __restrict__ linb,
    float* __restrict__ out)
{
    __shared__ __align__(16) unsigned char smem[4096];   // 2 bufs x 16 batch x 128B
    const int tid  = (int)threadIdx.x;
    const int lane = tid & 63;
    const int w    = tid >> 6;       // wave 0..3, owns j in [16w, 16w+16)
    const int c    = lane & 15;      // batch col within group
    const int q    = lane >> 4;      // quarter group
    const int b    = (int)blockIdx.x * 16 + c;
    const float* sc = in + (size_t)b * (TSEQ * 2);

    // ---- encoder embedding base: eb[k] = vel_b[k] + PE[b][k]
    float eb[EMB];
    #pragma unroll
    for (int i = 0; i < 4; ++i) {
        float div = __expf((float)(2*i) * -1.1512925464970229f); // -ln(10000)/8
        float arg = (float)b * div;
        eb[2*i]   = velb[2*i]   + __sinf(arg);
        eb[2*i+1] = velb[2*i+1] + __cosf(arg);
    }

    // ---- folded + activation-scaled gi constants (encoder)
    f32x4 ARv,BRv,CRv, AZv,BZv,CZv, ANv,BNv,CNv, BHv;
    #pragma unroll
    for (int r_ = 0; r_ < 4; ++r_) {
        int j = 16*w + 4*q + r_;
        #pragma unroll
        for (int g = 0; g < 3; ++g) {
            int row = g*HID + j;
            float a = 0.f, bb = 0.f, cc = ebih[row];
            #pragma unroll
            for (int k = 0; k < EMB; ++k) {
                float wv = eWih[row*EMB + k];
                a  += wv * velW[2*k];
                bb += wv * velW[2*k+1];
                cc += wv * eb[k];
            }
            if      (g == 0) { ARv[r_]=SSIG*a; BRv[r_]=SSIG*bb; CRv[r_]=SSIG*(cc + ebhh[j]); }
            else if (g == 1) { AZv[r_]=SSIG*a; BZv[r_]=SSIG*bb; CZv[r_]=SSIG*(cc + ebhh[HID+j]); }
            else             { ANv[r_]=STAN*a; BNv[r_]=STAN*bb; CNv[r_]=STAN*cc; BHv[r_]=STAN*ebhh[2*HID+j]; }
        }
    }

    // ---- A-fragments (weights pre-scaled): tile (g*4+w), row=16*tile+c, k=32kk+8q+i
    short8 AF0k0 = pack_row8(eWhh + (16*(0+w)+c)*HID      + 8*q, SSIG);
    short8 AF0k1 = pack_row8(eWhh + (16*(0+w)+c)*HID + 32 + 8*q, SSIG);
    short8 AF1k0 = pack_row8(eWhh + (16*(4+w)+c)*HID      + 8*q, SSIG);
    short8 AF1k1 = pack_row8(eWhh + (16*(4+w)+c)*HID + 32 + 8*q, SSIG);
    short8 AF2k0 = pack_row8(eWhh + (16*(8+w)+c)*HID      + 8*q, STAN);
    short8 AF2k1 = pack_row8(eWhh + (16*(8+w)+c)*HID + 32 + 8*q, STAN);

    // ---- LDS addresses (XOR-swizzled within each 128B batch-row).
    // NOTE: the +64 of the second B-frag must be inside the XOR (swz has bit 6!)
    const int swz = (c & 7) << 4;
    unsigned char* wptr        = smem + c*128 + ((32*w + 8*q) ^ swz);  // write: 4 h (8B)
    const unsigned char* rptr0 = smem + c*128 + ((16*q     ) ^ swz);   // B-frag kk=0
    const unsigned char* rptr1 = smem + c*128 + ((16*q + 64) ^ swz);   // B-frag kk=1

    *(uint2*)(wptr) = make_uint2(0u, 0u);   // h0 = 0 into buf0
    group_barrier();

    float h0=0.f, h1=0.f, h2=0.f, h3=0.f;

#define STEP(BUF, DX, DY) { \
    U16x8 b0_, b1_; \
    b0_.v = *(const uint4*)(rptr0 + (BUF)*2048); \
    b1_.v = *(const uint4*)(rptr1 + (BUF)*2048); \
    const float dx_ = (DX), dy_ = (DY); \
    f32x4 aR_, aZ_; float gN_[4]; \
    _Pragma("unroll") \
    for (int r_ = 0; r_ < 4; ++r_) { \
        aR_[r_] = fmaf(BRv[r_], dy_, fmaf(ARv[r_], dx_, CRv[r_])); \
        aZ_[r_] = fmaf(BZv[r_], dy_, fmaf(AZv[r_], dx_, CZv[r_])); \
        gN_[r_] = fmaf(BNv[r_], dy_, fmaf(ANv[r_], dx_, CNv[r_])); \
    } \
    aR_ = __builtin_amdgcn_mfma_f32_16x16x32_bf16(AF0k0, b0_.s, aR_, 0,0,0); \
    aR_ = __builtin_amdgcn_mfma_f32_16x16x32_bf16(AF0k1, b1_.s, aR_, 0,0,0); \
    aZ_ = __builtin_amdgcn_mfma_f32_16x16x32_bf16(AF1k0, b0_.s, aZ_, 0,0,0); \
    aZ_ = __builtin_amdgcn_mfma_f32_16x16x32_bf16(AF1k1, b1_.s, aZ_, 0,0,0); \
    f32x4 aN_ = __builtin_amdgcn_mfma_f32_16x16x32_bf16(AF2k0, b0_.s, BHv, 0,0,0); \
    aN_ = __builtin_amdgcn_mfma_f32_16x16x32_bf16(AF2k1, b1_.s, aN_, 0,0,0); \
    float hh_[4] = {h0, h1, h2, h3}; \
    _Pragma("unroll") \
    for (int r_ = 0; r_ < 4; ++r_) { \
        float rr = frcp(1.0f + fexp2(aR_[r_])); \
        float zz = frcp(1.0f + fexp2(aZ_[r_])); \
        float uu = fmaf(rr, aN_[r_], gN_[r_]); \
        float dd = frcp(1.0f + fexp2(uu)); \
        float nn = fmaf(-2.0f, dd, 1.0f); \
        hh_[r_] = fmaf(zz, hh_[r_] - nn, nn); \
    } \
    h0=hh_[0]; h1=hh_[1]; h2=hh_[2]; h3=hh_[3]; \
    *(uint2*)(wptr + ((BUF)^1)*2048) = make_uint2(cvt_pk_bf16(h0,h1), cvt_pk_bf16(h2,h3)); \
    group_barrier(); }

    // ================= encoder: 2047 steps, 4 per iter =================
    const float4* gp = (const float4*)(sc);
    float4 P0 = gp[0], P1 = gp[1];
    gp += 2;
    for (int k = 0; k < (TSEQ/4) - 1; ++k) {       // 511 iters -> steps 0..2043
        float4 N0 = gp[0], N1 = gp[1];             // prefetch points 4k+4..4k+7
        gp += 2;
        STEP(0, P0.z - P0.x, P0.w - P0.y);
        STEP(1, P1.x - P0.z, P1.y - P0.w);
        STEP(0, P1.z - P1.x, P1.w - P1.y);
        STEP(1, N0.x - P1.z, N0.y - P1.w);
        P0 = N0; P1 = N1;
    }
    // tail: P0,P1 = points 2044..2047, steps 2044..2046
    STEP(0, P0.z - P0.x, P0.w - P0.y);
    STEP(1, P1.x - P0.z, P1.y - P0.w);
    STEP(0, P1.z - P1.x, P1.w - P1.y);
    // final h now in buf1

    // ================= decoder setup =================
    float px0 = P1.z - P1.x, px1 = P1.w - P1.y;    // diffs[:, -1]
    float off0 = P1.z, off1 = P1.w;                // input_seq[:, -1, :2]

    #pragma unroll
    for (int r_ = 0; r_ < 4; ++r_) {
        int j = 16*w + 4*q + r_;
        #pragma unroll
        for (int g = 0; g < 3; ++g) {
            int row = g*HID + j;
            float a = 0.f, bb = 0.f, cc = dbih[row];
            #pragma unroll
            for (int k = 0; k < EMB; ++k) {
                float wv = dWih[row*EMB + k];
                a  += wv * velW[2*k];
                bb += wv * velW[2*k+1];
                cc += wv * velb[k];     // no PE in decoder
            }
            if      (g == 0) { ARv[r_]=SSIG*a; BRv[r_]=SSIG*bb; CRv[r_]=SSIG*(cc + dbhh[j]); }
            else if (g == 1) { AZv[r_]=SSIG*a; BZv[r_]=SSIG*bb; CZv[r_]=SSIG*(cc + dbhh[HID+j]); }
            else             { ANv[r_]=STAN*a; BNv[r_]=STAN*bb; CNv[r_]=STAN*cc; BHv[r_]=STAN*dbhh[2*HID+j]; }
        }
    }
    AF0k0 = pack_row8(dWhh + (16*(0+w)+c)*HID      + 8*q, SSIG);
    AF0k1 = pack_row8(dWhh + (16*(0+w)+c)*HID + 32 + 8*q, SSIG);
    AF1k0 = pack_row8(dWhh + (16*(4+w)+c)*HID      + 8*q, SSIG);
    AF1k1 = pack_row8(dWhh + (16*(4+w)+c)*HID + 32 + 8*q, SSIG);
    AF2k0 = pack_row8(dWhh + (16*(8+w)+c)*HID      + 8*q, STAN);
    AF2k1 = pack_row8(dWhh + (16*(8+w)+c)*HID + 32 + 8*q, STAN);

    float lw0[16], lw1[16];
    #pragma unroll
    for (int u = 0; u < 16; ++u) {
        lw0[u] = linW[16*q + u];
        lw1[u] = linW[HID + 16*q + u];
    }
    const float lb0 = linb[0], lb1 = linb[1];
    float* outp = out + (size_t)b * SDEC * 2;
    const int xoff0 = c*128 + ((32*q) ^ swz);
    const int xoff1 = c*128 + ((32*q + 16) ^ swz);

    // ================= decoder: 20 steps (starts reading buf1) =================
    int cur = 1;
    for (int s = 0; s < SDEC; ++s) {
        U16x8 b0_, b1_;
        b0_.v = *(const uint4*)(rptr0 + cur*2048);
        b1_.v = *(const uint4*)(rptr1 + cur*2048);
        f32x4 aR_, aZ_; float gN_[4];
        #pragma unroll
        for (int r_ = 0; r_ < 4; ++r_) {
            aR_[r_] = fmaf(BRv[r_], px1, fmaf(ARv[r_], px0, CRv[r_]));
            aZ_[r_] = fmaf(BZv[r_], px1, fmaf(AZv[r_], px0, CZv[r_]));
            gN_[r_] = fmaf(BNv[r_], px1, fmaf(ANv[r_], px0, CNv[r_]));
        }
        aR_ = __builtin_amdgcn_mfma_f32_16x16x32_bf16(AF0k0, b0_.s, aR_, 0,0,0);
        aR_ = __builtin_amdgcn_mfma_f32_16x16x32_bf16(AF0k1, b1_.s, aR_, 0,0,0);
        aZ_ = __builtin_amdgcn_mfma_f32_16x16x32_bf16(AF1k0, b0_.s, aZ_, 0,0,0);
        aZ_ = __builtin_amdgcn_mfma_f32_16x16x32_bf16(AF1k1, b1_.s, aZ_, 0,0,0);
        f32x4 aN_ = __builtin_amdgcn_mfma_f32_16x16x32_bf16(AF2k0, b0_.s, BHv, 0,0,0);
        aN_ = __builtin_amdgcn_mfma_f32_16x16x32_bf16(AF2k1, b1_.s, aN_, 0,0,0);
        float hh_[4] = {h0, h1, h2, h3};
        #pragma unroll
        for (int r_ = 0; r_ < 4; ++r_) {
            float rr = frcp(1.0f + fexp2(aR_[r_]));
            float zz = frcp(1.0f + fexp2(aZ_[r_]));
            float uu = fmaf(rr, aN_[r_], gN_[r_]);
            float dd = frcp(1.0f + fexp2(uu));
            float nn = fmaf(-2.0f, dd, 1.0f);
            hh_[r_] = fmaf(zz, hh_[r_] - nn, nn);
        }
        h0=hh_[0]; h1=hh_[1]; h2=hh_[2]; h3=hh_[3];
        *(uint2*)(wptr + (cur^1)*2048) = make_uint2(cvt_pk_bf16(h0,h1), cvt_pk_bf16(h2,h3));
        group_barrier();

        // x = h_new @ lin_W.T + lin_b + prev_x  (read h_new from LDS, reduce over q)
        U16x8 xu0, xu1;
        xu0.v = *(const uint4*)(smem + (cur^1)*2048 + xoff0);
        xu1.v = *(const uint4*)(smem + (cur^1)*2048 + xoff1);
        float s0 = 0.f, s1 = 0.f;
        #pragma unroll
        for (int i = 0; i < 8; ++i) {
            unsigned dw = (i < 4) ? xu0.u[i] : xu1.u[i-4];
            float hlo = __uint_as_float(dw << 16);
            float hhi = __uint_as_float(dw & 0xffff0000u);
            s0 = fmaf(hlo, lw0[2*i], fmaf(hhi, lw0[2*i+1], s0));
            s1 = fmaf(hlo, lw1[2*i], fmaf(hhi, lw1[2*i+1], s1));
        }
        s0 += __shfl_xor(s0, 16); s0 += __shfl_xor(s0, 32);
        s1 += __shfl_xor(s1, 16); s1 += __shfl_xor(s1, 32);
        float x0 = s0 + lb0 + px0;
        float x1 = s1 + lb1 + px1;
        if (tid < 16) *(float2*)(outp + 2*s) = make_float2(x0 + off0, x1 + off1);
        px0 = x0; px1 = x1;
        cur ^= 1;
    }
#undef STEP
}

extern "C" void kernel_launch(void* const* d_in, const int* in_sizes, int n_in,
                              void* d_out, int out_size, void* d_ws, size_t ws_size,
                              hipStream_t stream) {
    const float* input_seq = (const float*)d_in[0];
    const float* vel_W   = (const float*)d_in[1];
    const float* vel_b   = (const float*)d_in[2];
    const float* enc_Wih = (const float*)d_in[3];
    const float* enc_Whh = (const float*)d_in[4];
    const float* enc_bih = (const float*)d_in[5];
    const float* enc_bhh = (const float*)d_in[6];
    const float* dec_Wih = (const float*)d_in[7];
    const float* dec_Whh = (const float*)d_in[8];
    const float* dec_bih = (const float*)d_in[9];
    const float* dec_bhh = (const float*)d_in[10];
    const float* lin_W   = (const float*)d_in[11];
    const float* lin_b   = (const float*)d_in[12];
    float* out = (float*)d_out;

    int B = in_sizes[0] / (TSEQ * 2);     // 4096
    int blocks = B / 16;                  // 256 workgroups, 1 per CU
    gru_mfma_kernel<<<blocks, 256, 0, stream>>>(
        input_seq, vel_W, vel_b, enc_Wih, enc_Whh, enc_bih, enc_bhh,
        dec_Wih, dec_Whh, dec_bih, dec_bhh, lin_W, lin_b, out);
}